// Round 7
// baseline (427.873 us; speedup 1.0000x reference)
//
#include <hip/hip_runtime.h>
#include <stdint.h>

// WhiteboxGATBlock: N=100000, D=256, K=4, R=16, E=1700000 (1.6M rand + 100k self-loops)
// All tensors fp32. Algebra:
//   M = 0.5*(D - (D^T D) D), A = I + M
//   H = 0.5*Z + 0.5*V@W  (V = head-weighted normalized attention agg, W[j][d]=U[j>>4][d][j&15])
//   out = relu(H@A - 0.05) = relu( Z@(0.5A) + V@(0.5*W@A) - 0.05 )
// => fused MFMA GEMM K=320 over [Zb | Vb] @ Bt. ZU for attention logits is ALSO an MFMA GEMM.
// Edge softmax: shift-invariant; self-loop guarantees denom > 0; fp32-safe without segmax.
// CSR build: deterministic two-level partition (bucket = dst>>8), LDS cursors only.
//
// R1: LDS-staged k_out/k_zumm. 470->445. R2: bf16 ZU. R3: reg-staging (compiler sank). ->417.
// R4: k_zumm no-LDS direct frags; k_out global_load_lds. flat. R5/R6: fenced phases — flat,
//     VGPR=40, occ 45%: store-drain theory REFUTED. All k_zumm variants 70-77us.
// R7 change (theory: per-instruction SEGMENT utilization. Old fragment load: 64 lanes ->
//   16 rows x 4 chunks at 32B stride = 32 distinct 64B segments, 16B used each (25%).
//   25% x 6.3TB/s = 1.57 TB/s = measured. Scheduling-invariant => matches R4/R5/R6 nulls.):
//   k-PERMUTATION: lane (m16,quad) loads CONTIGUOUS 16B chunks (full 64B segments/instr):
//     z_k(ks,quad,j) = ks*32 + (j<4 ? quad*4+j : 16+quad*4+j-4)
//   Same permutation applied to U2t (prep5) and Bt rows k<256 (prep3) => GEMM sums unchanged.
//   Zb is stored k-permuted; k_out consumes permuted Zb against permuted Bt consistently.
//   Also: prep1/2/4 register-tiled 4-wide (were 2 scalar L2 loads per FMA).

typedef unsigned short u16;
typedef unsigned int u32;
typedef __attribute__((ext_vector_type(8))) short bf16x8;   // 4 VGPRs, MFMA A/B frag
typedef __attribute__((ext_vector_type(4))) float f32x4;    // MFMA C/D frag

#define PB 256   // partition blocks

__device__ __forceinline__ u16 f2bf(float f) {
    u32 u = __float_as_uint(f);
    u32 r = u + 0x7fffu + ((u >> 16) & 1u);   // RNE
    return (u16)(r >> 16);
}
__device__ __forceinline__ float bl(u32 p) { return __uint_as_float(p << 16); }
__device__ __forceinline__ float bh(u32 p) { return __uint_as_float(p & 0xffff0000u); }

// mfma-k -> z-k permutation (must match k_zumm's pack order)
__device__ __forceinline__ int kperm(int dm) {
    int rr = dm & 31, q = rr >> 3, j = rr & 7;
    return (dm & ~31) + (j < 4 ? q * 4 + j : 16 + q * 4 + (j - 4));
}

__device__ __forceinline__ void gload_lds16(const void* g, void* l) {
    __builtin_amdgcn_global_load_lds(
        (const __attribute__((address_space(1))) void*)g,
        (__attribute__((address_space(3))) void*)l, 16, 0, 0);
}

// ---------- prep: G = D^T D (256x256), 4 outputs/thread, row-coalesced ----------
__global__ __launch_bounds__(64) void k_prep1(const float* __restrict__ D, float* __restrict__ G) {
    int i = blockIdx.x, j0 = threadIdx.x * 4;
    float4 acc = {0.f, 0.f, 0.f, 0.f};
    for (int d = 0; d < 256; ++d) {
        float s = D[d * 256 + i];                     // block-uniform (SGPR)
        float4 b = *reinterpret_cast<const float4*>(D + d * 256 + j0);
        acc.x += s * b.x; acc.y += s * b.y; acc.z += s * b.z; acc.w += s * b.w;
    }
    *reinterpret_cast<float4*>(G + i * 256 + j0) = acc;
}

// ---------- prep: A = I + 0.5*(D - G@D)  (fp32), 4 outputs/thread ----------
__global__ __launch_bounds__(64) void k_prep2(const float* __restrict__ D, const float* __restrict__ G,
                                              float* __restrict__ A) {
    int tR = blockIdx.x, j0 = threadIdx.x * 4;
    float4 acc = {0.f, 0.f, 0.f, 0.f};
    for (int u = 0; u < 256; ++u) {
        float s = G[tR * 256 + u];                    // block-uniform
        float4 b = *reinterpret_cast<const float4*>(D + u * 256 + j0);
        acc.x += s * b.x; acc.y += s * b.y; acc.z += s * b.z; acc.w += s * b.w;
    }
    float4 dv = *reinterpret_cast<const float4*>(D + tR * 256 + j0);
    float4 o;
    o.x = 0.5f * (dv.x - acc.x) + (tR == j0 + 0 ? 1.f : 0.f);
    o.y = 0.5f * (dv.y - acc.y) + (tR == j0 + 1 ? 1.f : 0.f);
    o.z = 0.5f * (dv.z - acc.z) + (tR == j0 + 2 ? 1.f : 0.f);
    o.w = 0.5f * (dv.w - acc.w) + (tR == j0 + 3 ? 1.f : 0.f);
    *reinterpret_cast<float4*>(A + tR * 256 + j0) = o;
}

// ---------- prep: Bt[c][k] = bf16(0.5*A[kperm(k)][c]) for k<256 (B stored [col][k]) ----------
__global__ void k_prep3(const float* __restrict__ A, u16* __restrict__ Bt) {
    int c = blockIdx.x, k = threadIdx.x;
    Bt[c * 320 + k] = f2bf(0.5f * A[kperm(k) * 256 + c]);
}

// ---------- prep: Bt[c][256+j] = bf16(0.5 * sum_d W[j][d]*A[d][c]), 4 c's/thread ----------
__global__ __launch_bounds__(64) void k_prep4(const float* __restrict__ U, const float* __restrict__ A,
                                              u16* __restrict__ Bt) {
    int j = blockIdx.x;
    int k = j >> 4, r = j & 15;
    int c0 = threadIdx.x * 4;
    float4 acc = {0.f, 0.f, 0.f, 0.f};
    for (int d = 0; d < 256; ++d) {
        float s = U[k * 4096 + d * 16 + r];           // block-uniform
        float4 b = *reinterpret_cast<const float4*>(A + d * 256 + c0);
        acc.x += s * b.x; acc.y += s * b.y; acc.z += s * b.z; acc.w += s * b.w;
    }
    Bt[(c0 + 0) * 320 + 256 + j] = f2bf(0.5f * acc.x);
    Bt[(c0 + 1) * 320 + 256 + j] = f2bf(0.5f * acc.y);
    Bt[(c0 + 2) * 320 + 256 + j] = f2bf(0.5f * acc.z);
    Bt[(c0 + 3) * 320 + 256 + j] = f2bf(0.5f * acc.w);
}

// ---------- prep: U2t[j][d] = bf16(U[j>>4][kperm(d)][j&15])  (64x256, k-permuted) ----------
__global__ void k_prep5(const float* __restrict__ U, u16* __restrict__ U2t) {
    int j = blockIdx.x, d = threadIdx.x;
    int dz = kperm(d);
    U2t[j * 256 + d] = f2bf(U[(j >> 4) * 4096 + dz * 16 + (j & 15)]);
}

// ---------- partition pass 1: per-block histogram over coarse buckets ----------
__global__ __launch_bounds__(256) void k_cnt1(const int* __restrict__ ei,
                                              int* __restrict__ cnt2, int E, int nbuck) {
    __shared__ int h[512];
    int t = threadIdx.x, b = blockIdx.x;
    for (int i = t; i < nbuck; i += 256) h[i] = 0;
    __syncthreads();
    int per = (E + PB - 1) / PB;
    int lo = b * per;
    int hi = lo + per; if (hi > E) hi = E;
    for (int e = lo + t; e < hi; e += 256)
        atomicAdd(&h[ei[E + e] >> 8], 1);
    __syncthreads();
    for (int i = t; i < nbuck; i += 256)
        cnt2[b * nbuck + i] = h[i];
}

// ---------- partition pass 2a: per-bucket scan across blocks ----------
__global__ __launch_bounds__(256) void k_cscan1(const int* __restrict__ cnt2,
                                                int* __restrict__ pre2,
                                                int* __restrict__ tot, int nbuck) {
    __shared__ int s[256];
    int t = threadIdx.x, b = blockIdx.x;
    int v = cnt2[t * nbuck + b];
    s[t] = v;
    __syncthreads();
    for (int o = 1; o < 256; o <<= 1) {
        int x = (t >= o) ? s[t - o] : 0;
        __syncthreads();
        s[t] += x;
        __syncthreads();
    }
    pre2[t * nbuck + b] = s[t] - v;
    if (t == 255) tot[b] = s[255];
}

// ---------- partition pass 2b: scan bucket totals ----------
__global__ __launch_bounds__(512) void k_cscan2(const int* __restrict__ tot,
                                                int* __restrict__ bbase, int nbuck) {
    __shared__ int s[512];
    int t = threadIdx.x;
    int v = (t < nbuck) ? tot[t] : 0;
    s[t] = v;
    __syncthreads();
    for (int o = 1; o < 512; o <<= 1) {
        int x = (t >= o) ? s[t - o] : 0;
        __syncthreads();
        s[t] += x;
        __syncthreads();
    }
    if (t < nbuck) bbase[t] = s[t] - v;
}

// ---------- partition pass 3: place packed (src<<8 | dst&255) into coarse buckets ----------
__global__ __launch_bounds__(256) void k_place(const int* __restrict__ ei,
                                               const int* __restrict__ pre2,
                                               const int* __restrict__ bbase,
                                               int* __restrict__ part, int E, int nbuck) {
    __shared__ int baseS[512];
    __shared__ int cur[512];
    int t = threadIdx.x, b = blockIdx.x;
    for (int i = t; i < nbuck; i += 256) {
        baseS[i] = bbase[i] + pre2[b * nbuck + i];
        cur[i] = 0;
    }
    __syncthreads();
    int per = (E + PB - 1) / PB;
    int lo = b * per;
    int hi = lo + per; if (hi > E) hi = E;
    for (int e = lo + t; e < hi; e += 256) {
        int s = ei[e];
        int d = ei[E + e];
        int bk = d >> 8;
        int r = atomicAdd(&cur[bk], 1);          // LDS atomic
        part[baseS[bk] + r] = (s << 8) | (d & 255);
    }
}

// ---------- partition pass 4: within-bucket CSR finalize (off/cnt/esrc), LDS cursors ----------
__global__ __launch_bounds__(256) void k_bucket(const int* __restrict__ part,
                                                const int* __restrict__ tot,
                                                const int* __restrict__ bbase,
                                                int* __restrict__ off,
                                                int* __restrict__ cnt,
                                                int* __restrict__ esrc, int n) {
    __shared__ int ncnt[256], excl[256], cur[256], sc[256];
    int t = threadIdx.x, b = blockIdx.x;
    ncnt[t] = 0;
    cur[t] = 0;
    __syncthreads();
    int base = bbase[b], m = tot[b];
    for (int i = t; i < m; i += 256)
        atomicAdd(&ncnt[part[base + i] & 255], 1);
    __syncthreads();
    int v = ncnt[t];
    sc[t] = v;
    __syncthreads();
    for (int o = 1; o < 256; o <<= 1) {
        int x = (t >= o) ? sc[t - o] : 0;
        __syncthreads();
        sc[t] += x;
        __syncthreads();
    }
    excl[t] = sc[t] - v;
    int node = b * 256 + t;
    if (node < n) {
        off[node] = base + excl[t];
        cnt[node] = v;
    }
    __syncthreads();
    for (int i = t; i < m; i += 256) {
        int pk = part[base + i];
        int j = pk & 255;
        int r = atomicAdd(&cur[j], 1);           // LDS atomic
        esrc[base + excl[j] + r] = pk >> 8;
    }
}

// ---------- ZU = bf16(Z) @ U2t^T via MFMA (bf16 out), fused cast (emits k-permuted Zb) ----------
// R7: contiguous-instruction loads. Per ks, two loads at row*1024 + ks*128 + quad*16 (+64):
// each instruction = 16 rows x one FULL 64B segment (100% utilization, was 25%).
// Lane's 8 elements land in kperm order; U2t/Bt are pre-permuted to match.
__global__ __launch_bounds__(256, 4) void k_zumm(const float* __restrict__ Z,
                                                 const u16* __restrict__ U2t,
                                                 u16* __restrict__ ZUb,
                                                 u16* __restrict__ Zb, int n) {
    const int t = threadIdx.x;
    const int w = t >> 6;
    const int lane = t & 63;
    const int m16 = lane & 15;
    const int quad = lane >> 4;
    const int nb = blockIdx.x * 64;
    const int row = nb + w * 16 + m16;
    const int rowc = row < n ? row : n - 1;
    const char* zrow = (const char*)(Z + (size_t)rowc * 256);

    // phase 1: 16 loads, each fully segment-coalesced (16 rows x 64B)
    float4 zf0[8], zf1[8];
#pragma unroll
    for (int ks = 0; ks < 8; ++ks) {
        zf0[ks] = *reinterpret_cast<const float4*>(zrow + ks * 128 + quad * 16);
        zf1[ks] = *reinterpret_cast<const float4*>(zrow + ks * 128 + 64 + quad * 16);
    }
    __builtin_amdgcn_sched_barrier(0);

    // phase 2: pack (lane holds z_k = ks*32 + {quad*4+[0,4), 16+quad*4+[0,4)})
    uint4 pk[8];
#pragma unroll
    for (int ks = 0; ks < 8; ++ks) {
        pk[ks].x = (u32)f2bf(zf0[ks].x) | ((u32)f2bf(zf0[ks].y) << 16);
        pk[ks].y = (u32)f2bf(zf0[ks].z) | ((u32)f2bf(zf0[ks].w) << 16);
        pk[ks].z = (u32)f2bf(zf1[ks].x) | ((u32)f2bf(zf1[ks].y) << 16);
        pk[ks].w = (u32)f2bf(zf1[ks].z) | ((u32)f2bf(zf1[ks].w) << 16);
    }
    __builtin_amdgcn_sched_barrier(0);

    // phase 3: MFMA loop — only U2t loads (L1-hot) in the vmcnt stream
    f32x4 acc[4];
#pragma unroll
    for (int nt = 0; nt < 4; ++nt) acc[nt] = (f32x4){0.f, 0.f, 0.f, 0.f};
#pragma unroll
    for (int ks = 0; ks < 8; ++ks) {
        bf16x8 a;
        __builtin_memcpy(&a, &pk[ks], 16);
#pragma unroll
        for (int nt = 0; nt < 4; ++nt) {
            bf16x8 b = *reinterpret_cast<const bf16x8*>(
                U2t + (size_t)(nt * 16 + m16) * 256 + ks * 32 + quad * 8);
            acc[nt] = __builtin_amdgcn_mfma_f32_16x16x32_bf16(a, b, acc[nt], 0, 0, 0);
        }
    }
    __builtin_amdgcn_sched_barrier(0);

    // phase 4: epilogue stores. Zb[row][ks*32+quad*8..] = pk[ks]  (k-permuted layout;
    // bytes row*512 + ks*64 + quad*16 -> full 64B segments per instruction)
    if (row < n) {
#pragma unroll
        for (int ks = 0; ks < 8; ++ks)
            *reinterpret_cast<uint4*>(Zb + (size_t)row * 256 + ks * 32 + quad * 8) = pk[ks];
    }
    // D: row=quad*4+r (node), col=m16 (output within nt tile); store bf16
#pragma unroll
    for (int r = 0; r < 4; ++r) {
        int node = nb + w * 16 + quad * 4 + r;
        if (node < n) {
#pragma unroll
            for (int nt = 0; nt < 4; ++nt)
                ZUb[(size_t)node * 64 + nt * 16 + m16] = f2bf(acc[nt][r]);
        }
    }
}

// ---------- per-node aggregation: 1 wave/node, 4 edges in flight; emits bf16 V ----------
// lane = g*16+q: group g handles edge c0+g, lane q holds dims 4q..4q+3 (uint2 bf16x4)
// 2-deep esrc index pipeline + 1-deep ZUb gather pipeline.
__global__ __launch_bounds__(256) void k_agg(const u16* __restrict__ ZUb,
                                             const int* __restrict__ esrc,
                                             const int* __restrict__ off,
                                             const int* __restrict__ cnt,
                                             const float* __restrict__ hwp,
                                             u16* __restrict__ Vb, int n) {
    int node = blockIdx.x * 4 + (threadIdx.x >> 6);
    int lane = threadIdx.x & 63;
    if (node >= n) return;
    const int q = lane & 15;
    const int g = lane >> 4;
    uint2 zdp = *reinterpret_cast<const uint2*>(ZUb + (size_t)node * 64 + q * 4);
    float zd0 = bl(zdp.x), zd1 = bh(zdp.x), zd2 = bl(zdp.y), zd3 = bh(zdp.y);
    int base = off[node];
    int deg = cnt[node];

    int s0 = (g < deg) ? esrc[base + g] : 0;
    int s1 = (4 + g < deg) ? esrc[base + 4 + g] : 0;
    uint2 z0 = *reinterpret_cast<const uint2*>(ZUb + (size_t)s0 * 64 + q * 4);

    float ax = 0.f, ay = 0.f, az = 0.f, aw = 0.f, ssum = 0.f;
    for (int c0 = 0; c0 < deg; c0 += 4) {
        int e2 = c0 + 8 + g;
        int s2 = (e2 < deg) ? esrc[base + e2] : 0;          // index prefetch (k+2)
        uint2 z1 = *reinterpret_cast<const uint2*>(           // gather prefetch (k+1)
            ZUb + (size_t)s1 * 64 + q * 4);
        bool valid = (c0 + g) < deg;
        float v0 = bl(z0.x), v1 = bh(z0.x), v2 = bl(z0.y), v3 = bh(z0.y);
        float p = v0 * zd0 + v1 * zd1 + v2 * zd2 + v3 * zd3;
        p += __shfl_xor(p, 1);
        p += __shfl_xor(p, 2);              // head dot across 4-lane subgroup
        float ew = valid ? __expf(p * 0.25f) : 0.f;   // / sqrt(R)=4
        ax += ew * v0; ay += ew * v1;
        az += ew * v2; aw += ew * v3;
        ssum += ew;
        s1 = s2; z0 = z1;
    }
    ax += __shfl_xor(ax, 16); ax += __shfl_xor(ax, 32);
    ay += __shfl_xor(ay, 16); ay += __shfl_xor(ay, 32);
    az += __shfl_xor(az, 16); az += __shfl_xor(az, 32);
    aw += __shfl_xor(aw, 16); aw += __shfl_xor(aw, 32);
    ssum += __shfl_xor(ssum, 16); ssum += __shfl_xor(ssum, 32);

    if (g == 0) {
        float h0 = hwp[0], h1 = hwp[1], h2 = hwp[2], h3 = hwp[3];
        float mx = fmaxf(fmaxf(h0, h1), fmaxf(h2, h3));
        float e0 = __expf(h0 - mx), e1 = __expf(h1 - mx),
              e2 = __expf(h2 - mx), e3 = __expf(h3 - mx);
        float es = e0 + e1 + e2 + e3;
        int hd = q >> 2;
        float wk = (hd == 0 ? e0 : hd == 1 ? e1 : hd == 2 ? e2 : e3) / es;
        float inv = wk / ssum;
        uint2 pk;
        pk.x = (u32)f2bf(ax * inv) | ((u32)f2bf(ay * inv) << 16);
        pk.y = (u32)f2bf(az * inv) | ((u32)f2bf(aw * inv) << 16);
        *reinterpret_cast<uint2*>(&Vb[(size_t)node * 64 + q * 4]) = pk;
    }
}

// ---------- final fused GEMM: out = relu([Zb|Vb] @ Bt^T - 0.05), K=320, bf16 MFMA ----------
// A-tile staged via async global_load_lds w=16, PRE-SWIZZLED global source; ds_reads use
// the same XOR -> conflict-free. Zb and Bt(k<256) are both k-permuted (consistent pair).
__global__ __launch_bounds__(256, 4) void k_out(const u16* __restrict__ Zb,
                                                const u16* __restrict__ Vb,
                                                const u16* __restrict__ Bt,
                                                float* __restrict__ out, int n) {
    __shared__ __align__(16) u16 sA[64 * 256];   // 32 KB, rows 512B (32 chunks)
    __shared__ __align__(16) u16 sV[64 * 64];    //  8 KB, rows 128B (8 chunks)
    const int t = threadIdx.x;
    const int w = t >> 6;
    const int lane = t & 63;
    const int m16 = lane & 15;          // A row / D col within tile
    const int quad = lane >> 4;         // k-subblock / D row group
    const int nb = blockIdx.x * 64;

    // stage Zb tile: LDS slot c holds global chunk (row, col^(row&7)).
#pragma unroll
    for (int i = 0; i < 8; ++i) {
        int c = i * 256 + w * 64 + lane;
        int row = c >> 5, col = c & 31;
        int scol = col ^ (row & 7);
        int gr = nb + row; if (gr >= n) gr = n - 1;
        gload_lds16(Zb + (size_t)gr * 256 + scol * 8,
                    sA + (size_t)(i * 256 + w * 64) * 8);
    }
    // stage Vb tile
#pragma unroll
    for (int i = 0; i < 2; ++i) {
        int c = i * 256 + w * 64 + lane;
        int row = c >> 3, col = c & 7;
        int scol = col ^ (row & 7);
        int gr = nb + row; if (gr >= n) gr = n - 1;
        gload_lds16(Vb + (size_t)gr * 64 + scol * 8,
                    sV + (size_t)(i * 256 + w * 64) * 8);
    }
    __syncthreads();   // compiler drains vmcnt before the barrier

    f32x4 acc[4][4];
#pragma unroll
    for (int mt = 0; mt < 4; ++mt)
#pragma unroll
        for (int nt = 0; nt < 4; ++nt)
            acc[mt][nt] = (f32x4){0.f, 0.f, 0.f, 0.f};

    const u16* bbase4[4];
#pragma unroll
    for (int nt = 0; nt < 4; ++nt)
        bbase4[nt] = Bt + (size_t)(w * 64 + nt * 16 + m16) * 320 + quad * 8;

    const u32 asw = (u32)(m16 & 7) << 4;

    for (int ks = 0; ks < 8; ++ks) {
        bf16x8 a[4], b[4];
#pragma unroll
        for (int mt = 0; mt < 4; ++mt)
            a[mt] = *reinterpret_cast<const bf16x8*>(
                (char*)sA + (u32)(mt * 16 + m16) * 512 +
                (((u32)(ks * 64 + quad * 16)) ^ asw));
#pragma unroll
        for (int nt = 0; nt < 4; ++nt)
            b[nt] = *reinterpret_cast<const bf16x8*>(bbase4[nt] + ks * 32);
#pragma unroll
        for (int mt = 0; mt < 4; ++mt)
#pragma unroll
            for (int nt = 0; nt < 4; ++nt)
                acc[mt][nt] = __builtin_amdgcn_mfma_f32_16x16x32_bf16(
                    a[mt], b[nt], acc[mt][nt], 0, 0, 0);
    }
#pragma unroll
    for (int ks = 8; ks < 10; ++ks) {
        bf16x8 a[4], b[4];
#pragma unroll
        for (int mt = 0; mt < 4; ++mt)
            a[mt] = *reinterpret_cast<const bf16x8*>(
                (char*)sV + (u32)(mt * 16 + m16) * 128 +
                (((u32)((ks - 8) * 64 + quad * 16)) ^ asw));
#pragma unroll
        for (int nt = 0; nt < 4; ++nt)
            b[nt] = *reinterpret_cast<const bf16x8*>(bbase4[nt] + ks * 32);
#pragma unroll
        for (int mt = 0; mt < 4; ++mt)
#pragma unroll
            for (int nt = 0; nt < 4; ++nt)
                acc[mt][nt] = __builtin_amdgcn_mfma_f32_16x16x32_bf16(
                    a[mt], b[nt], acc[mt][nt], 0, 0, 0);
    }

#pragma unroll
    for (int mt = 0; mt < 4; ++mt) {
#pragma unroll
        for (int r = 0; r < 4; ++r) {
            int row = nb + mt * 16 + quad * 4 + r;
            if (row < n) {
#pragma unroll
                for (int nt = 0; nt < 4; ++nt) {
                    int col = w * 64 + nt * 16 + m16;
                    out[(size_t)row * 256 + col] =
                        fmaxf(acc[mt][nt][r] - 0.05f, 0.f);
                }
            }
        }
    }
}

extern "C" void kernel_launch(void* const* d_in, const int* in_sizes, int n_in,
                              void* d_out, int out_size, void* d_ws, size_t ws_size,
                              hipStream_t stream) {
    const float* Z  = (const float*)d_in[0];
    const float* U  = (const float*)d_in[1];
    const float* Dm = (const float*)d_in[2];
    const float* hw = (const float*)d_in[3];
    const int*   ei = (const int*)d_in[4];
    const int n = in_sizes[0] / 256;       // 100000
    const int E = in_sizes[4] / 2;         // 1700000
    float* out = (float*)d_out;
    const int nbuck = (n + 255) >> 8;      // 391 (<= 512)

    // ws layout (~85 MB), lifetime-aliased:
    //   ZUb  bf16 n*64   (12.8 MB)  k_zumm -> k_agg
    //   Zb   bf16 n*256  (51.2 MB)  k_zumm -> k_out; OVERLAYS (dead after k_bucket):
    //        part int E (6.8 MB) | cnt2 int PB*nbuck | pre2 int PB*nbuck
    //   Vb   bf16 n*64   (12.8 MB)  k_agg -> k_out
    //   G, A fp32 64K ea; Bt bf16 256*320; U2t bf16 64*256
    //   esrc int E (6.8 MB)  k_bucket -> k_agg
    //   off, cnt int n; tot, bbase int nbuck
    char* wp = (char*)d_ws;
    u16* ZUb    = (u16*)wp;
    u16* Zb     = (u16*)(wp + (size_t)n * 128);
    int* part   = (int*)Zb;                 // aliases Zb (dead before k_zumm)
    int* cnt2   = part + E;
    int* pre2   = cnt2 + PB * nbuck;
    u16* Vb     = Zb + (size_t)n * 256;
    float* G    = (float*)(Vb + (size_t)n * 64);
    float* A    = G + 65536;
    u16* Bt     = (u16*)(A + 65536);
    u16* U2t    = Bt + 256 * 320;
    int* esrc   = (int*)(U2t + 64 * 256);
    int* off    = esrc + E;
    int* cnt    = off + n;
    int* tot    = cnt + n;
    int* bbase  = tot + nbuck;

    // prep (tiny)
    k_prep1<<<256, 64, 0, stream>>>(Dm, G);
    k_prep2<<<256, 64, 0, stream>>>(Dm, G, A);
    k_prep3<<<256, 256, 0, stream>>>(A, Bt);
    k_prep4<<<64, 64, 0, stream>>>(U, A, Bt);
    k_prep5<<<64, 256, 0, stream>>>(U, U2t);

    // CSR build (before k_zumm: part/cnt2/pre2 alias Zb)
    k_cnt1<<<PB, 256, 0, stream>>>(ei, cnt2, E, nbuck);
    k_cscan1<<<nbuck, 256, 0, stream>>>(cnt2, pre2, tot, nbuck);
    k_cscan2<<<1, 512, 0, stream>>>(tot, bbase, nbuck);
    k_place<<<PB, 256, 0, stream>>>(ei, pre2, bbase, part, E, nbuck);
    k_bucket<<<nbuck, 256, 0, stream>>>(part, tot, bbase, off, cnt, esrc, n);

    // main pipeline
    k_zumm<<<(n + 63) / 64, 256, 0, stream>>>(Z, U2t, ZUb, Zb, n);
    k_agg<<<(n + 3) / 4, 256, 0, stream>>>(ZUb, esrc, off, cnt, hw, Vb, n);
    k_out<<<(n + 63) / 64, 256, 0, stream>>>(Zb, Vb, Bt, out, n);
}

// Round 9
// 419.055 us; speedup vs baseline: 1.0210x; 1.0210x over previous
//
#include <hip/hip_runtime.h>
#include <stdint.h>

// WhiteboxGATBlock: N=100000, D=256, K=4, R=16, E=1700000 (1.6M rand + 100k self-loops)
// All tensors fp32. Algebra:
//   M = 0.5*(D - (D^T D) D), A = I + M
//   H = 0.5*Z + 0.5*V@W  (V = head-weighted normalized attention agg, W[j][d]=U[j>>4][d][j&15])
//   out = relu(H@A - 0.05) = relu( Z@(0.5A) + V@(0.5*W@A) - 0.05 )
// => fused MFMA GEMM K=320 over [bf16(Z) | Vb] @ Bt. ZU for logits is ALSO an MFMA GEMM.
// Edge softmax: shift-invariant; self-loop guarantees denom > 0; fp32-safe without segmax.
// CSR build: deterministic two-level partition (bucket = dst>>8), LDS cursors only.
//
// R1: LDS staging. R2: bf16 ZU. R3: reg-staging (compiler sank it). R4: no-LDS direct frags.
// R5/R6: fenced phases (store-drain scheduling theory refuted). R7: kperm full-segment loads
// (segment theory refuted). R8: inline-asm pinned loads — CRASHED (missing early-clobber on
// 16 outputs; no data; MLP question still open).
// R9 change (attack k_zumm's store TRAFFIC, not scheduling): ELIMINATE Zb entirely.
//   - k_zumm writes only ZUb (WRITE 62.5 -> 12.5 MB).
//   - k_out stages directly from Z (fp32), casts bf16 in-register during staging
//     (R1-R3 pattern), ds_writes the same swizzled LDS layout. Bt's kperm (prep3)
//     matches k_out's pack order by construction: chunk (row, ks*4+q) holds
//     z-elems {ks*32+q*4+[0,4), ks*32+16+q*4+[0,4)} = kperm(ks*32+q*8+[0,8)).

typedef unsigned short u16;
typedef unsigned int u32;
typedef __attribute__((ext_vector_type(8))) short bf16x8;   // 4 VGPRs, MFMA A/B frag
typedef __attribute__((ext_vector_type(4))) float f32x4;    // MFMA C/D frag

#define PB 256   // partition blocks

__device__ __forceinline__ u16 f2bf(float f) {
    u32 u = __float_as_uint(f);
    u32 r = u + 0x7fffu + ((u >> 16) & 1u);   // RNE
    return (u16)(r >> 16);
}
__device__ __forceinline__ float bl(u32 p) { return __uint_as_float(p << 16); }
__device__ __forceinline__ float bh(u32 p) { return __uint_as_float(p & 0xffff0000u); }

// mfma-k -> z-k permutation (must match k_zumm/k_out pack order)
__device__ __forceinline__ int kperm(int dm) {
    int rr = dm & 31, q = rr >> 3, j = rr & 7;
    return (dm & ~31) + (j < 4 ? q * 4 + j : 16 + q * 4 + (j - 4));
}

__device__ __forceinline__ void gload_lds16(const void* g, void* l) {
    __builtin_amdgcn_global_load_lds(
        (const __attribute__((address_space(1))) void*)g,
        (__attribute__((address_space(3))) void*)l, 16, 0, 0);
}

// ---------- prep: G = D^T D (256x256) ----------
__global__ void k_prep1(const float* __restrict__ D, float* __restrict__ G) {
    int i = blockIdx.x, j = threadIdx.x;
    float acc = 0.f;
    for (int d = 0; d < 256; ++d)
        acc += D[d * 256 + i] * D[d * 256 + j];
    G[i * 256 + j] = acc;
}

// ---------- prep: A = I + 0.5*(D - G@D)  (fp32) ----------
__global__ void k_prep2(const float* __restrict__ D, const float* __restrict__ G,
                        float* __restrict__ A) {
    int t = blockIdx.x, j = threadIdx.x;   // row t, col j
    float acc = 0.f;
    for (int u = 0; u < 256; ++u)
        acc += G[t * 256 + u] * D[u * 256 + j];
    A[t * 256 + j] = 0.5f * (D[t * 256 + j] - acc) + (t == j ? 1.f : 0.f);
}

// ---------- prep: Bt[c][k] = bf16(0.5*A[kperm(k)][c]) for k<256 (B stored [col][k]) ----------
__global__ void k_prep3(const float* __restrict__ A, u16* __restrict__ Bt) {
    int c = blockIdx.x, k = threadIdx.x;
    Bt[c * 320 + k] = f2bf(0.5f * A[kperm(k) * 256 + c]);
}

// ---------- prep: Bt[c][256+j] = bf16(0.5 * sum_d W[j][d]*A[d][c]) ----------
__global__ void k_prep4(const float* __restrict__ U, const float* __restrict__ A,
                        u16* __restrict__ Bt) {
    int j = blockIdx.x, c = threadIdx.x;
    int k = j >> 4, r = j & 15;
    float acc = 0.f;
    for (int d = 0; d < 256; ++d)
        acc += U[k * 4096 + d * 16 + r] * A[d * 256 + c];
    Bt[c * 320 + 256 + j] = f2bf(0.5f * acc);
}

// ---------- prep: U2t[j][d] = bf16(U[j>>4][kperm(d)][j&15])  (64x256, k-permuted) ----------
__global__ void k_prep5(const float* __restrict__ U, u16* __restrict__ U2t) {
    int j = blockIdx.x, d = threadIdx.x;
    int dz = kperm(d);
    U2t[j * 256 + d] = f2bf(U[(j >> 4) * 4096 + dz * 16 + (j & 15)]);
}

// ---------- partition pass 1: per-block histogram over coarse buckets ----------
__global__ __launch_bounds__(256) void k_cnt1(const int* __restrict__ ei,
                                              int* __restrict__ cnt2, int E, int nbuck) {
    __shared__ int h[512];
    int t = threadIdx.x, b = blockIdx.x;
    for (int i = t; i < nbuck; i += 256) h[i] = 0;
    __syncthreads();
    int per = (E + PB - 1) / PB;
    int lo = b * per;
    int hi = lo + per; if (hi > E) hi = E;
    for (int e = lo + t; e < hi; e += 256)
        atomicAdd(&h[ei[E + e] >> 8], 1);
    __syncthreads();
    for (int i = t; i < nbuck; i += 256)
        cnt2[b * nbuck + i] = h[i];
}

// ---------- partition pass 2a: per-bucket scan across blocks ----------
__global__ __launch_bounds__(256) void k_cscan1(const int* __restrict__ cnt2,
                                                int* __restrict__ pre2,
                                                int* __restrict__ tot, int nbuck) {
    __shared__ int s[256];
    int t = threadIdx.x, b = blockIdx.x;
    int v = cnt2[t * nbuck + b];
    s[t] = v;
    __syncthreads();
    for (int o = 1; o < 256; o <<= 1) {
        int x = (t >= o) ? s[t - o] : 0;
        __syncthreads();
        s[t] += x;
        __syncthreads();
    }
    pre2[t * nbuck + b] = s[t] - v;
    if (t == 255) tot[b] = s[255];
}

// ---------- partition pass 2b: scan bucket totals ----------
__global__ __launch_bounds__(512) void k_cscan2(const int* __restrict__ tot,
                                                int* __restrict__ bbase, int nbuck) {
    __shared__ int s[512];
    int t = threadIdx.x;
    int v = (t < nbuck) ? tot[t] : 0;
    s[t] = v;
    __syncthreads();
    for (int o = 1; o < 512; o <<= 1) {
        int x = (t >= o) ? s[t - o] : 0;
        __syncthreads();
        s[t] += x;
        __syncthreads();
    }
    if (t < nbuck) bbase[t] = s[t] - v;
}

// ---------- partition pass 3: place packed (src<<8 | dst&255) into coarse buckets ----------
__global__ __launch_bounds__(256) void k_place(const int* __restrict__ ei,
                                               const int* __restrict__ pre2,
                                               const int* __restrict__ bbase,
                                               int* __restrict__ part, int E, int nbuck) {
    __shared__ int baseS[512];
    __shared__ int cur[512];
    int t = threadIdx.x, b = blockIdx.x;
    for (int i = t; i < nbuck; i += 256) {
        baseS[i] = bbase[i] + pre2[b * nbuck + i];
        cur[i] = 0;
    }
    __syncthreads();
    int per = (E + PB - 1) / PB;
    int lo = b * per;
    int hi = lo + per; if (hi > E) hi = E;
    for (int e = lo + t; e < hi; e += 256) {
        int s = ei[e];
        int d = ei[E + e];
        int bk = d >> 8;
        int r = atomicAdd(&cur[bk], 1);          // LDS atomic
        part[baseS[bk] + r] = (s << 8) | (d & 255);
    }
}

// ---------- partition pass 4: within-bucket CSR finalize (off/cnt/esrc), LDS cursors ----------
__global__ __launch_bounds__(256) void k_bucket(const int* __restrict__ part,
                                                const int* __restrict__ tot,
                                                const int* __restrict__ bbase,
                                                int* __restrict__ off,
                                                int* __restrict__ cnt,
                                                int* __restrict__ esrc, int n) {
    __shared__ int ncnt[256], excl[256], cur[256], sc[256];
    int t = threadIdx.x, b = blockIdx.x;
    ncnt[t] = 0;
    cur[t] = 0;
    __syncthreads();
    int base = bbase[b], m = tot[b];
    for (int i = t; i < m; i += 256)
        atomicAdd(&ncnt[part[base + i] & 255], 1);
    __syncthreads();
    int v = ncnt[t];
    sc[t] = v;
    __syncthreads();
    for (int o = 1; o < 256; o <<= 1) {
        int x = (t >= o) ? sc[t - o] : 0;
        __syncthreads();
        sc[t] += x;
        __syncthreads();
    }
    excl[t] = sc[t] - v;
    int node = b * 256 + t;
    if (node < n) {
        off[node] = base + excl[t];
        cnt[node] = v;
    }
    __syncthreads();
    for (int i = t; i < m; i += 256) {
        int pk = part[base + i];
        int j = pk & 255;
        int r = atomicAdd(&cur[j], 1);           // LDS atomic
        esrc[base + excl[j] + r] = pk >> 8;
    }
}

// ---------- ZU = bf16(Z) @ U2t^T via MFMA (bf16 out). R9: NO Zb output. ----------
// Fenced phases: loads | pack | MFMA (U2t only in vmcnt stream) | ZUb stores.
// kperm contiguous loads: full 64B segments per instruction.
__global__ __launch_bounds__(256, 4) void k_zumm(const float* __restrict__ Z,
                                                 const u16* __restrict__ U2t,
                                                 u16* __restrict__ ZUb, int n) {
    const int t = threadIdx.x;
    const int w = t >> 6;
    const int lane = t & 63;
    const int m16 = lane & 15;
    const int quad = lane >> 4;
    const int nb = blockIdx.x * 64;
    const int row = nb + w * 16 + m16;
    const int rowc = row < n ? row : n - 1;
    const char* zrow = (const char*)(Z + (size_t)rowc * 256);

    // phase 1: 16 loads (full-segment)
    float4 zf0[8], zf1[8];
#pragma unroll
    for (int ks = 0; ks < 8; ++ks) {
        zf0[ks] = *reinterpret_cast<const float4*>(zrow + ks * 128 + quad * 16);
        zf1[ks] = *reinterpret_cast<const float4*>(zrow + ks * 128 + 64 + quad * 16);
    }
    __builtin_amdgcn_sched_barrier(0);

    // phase 2: pack (lane holds z_k = ks*32 + {quad*4+[0,4), 16+quad*4+[0,4)}) = kperm order
    uint4 pk[8];
#pragma unroll
    for (int ks = 0; ks < 8; ++ks) {
        pk[ks].x = (u32)f2bf(zf0[ks].x) | ((u32)f2bf(zf0[ks].y) << 16);
        pk[ks].y = (u32)f2bf(zf0[ks].z) | ((u32)f2bf(zf0[ks].w) << 16);
        pk[ks].z = (u32)f2bf(zf1[ks].x) | ((u32)f2bf(zf1[ks].y) << 16);
        pk[ks].w = (u32)f2bf(zf1[ks].z) | ((u32)f2bf(zf1[ks].w) << 16);
    }
    __builtin_amdgcn_sched_barrier(0);

    // phase 3: MFMA loop — only U2t loads (L1/L2-hot) in the vmcnt stream
    f32x4 acc[4];
#pragma unroll
    for (int nt = 0; nt < 4; ++nt) acc[nt] = (f32x4){0.f, 0.f, 0.f, 0.f};
#pragma unroll
    for (int ks = 0; ks < 8; ++ks) {
        bf16x8 a;
        __builtin_memcpy(&a, &pk[ks], 16);
#pragma unroll
        for (int nt = 0; nt < 4; ++nt) {
            bf16x8 b = *reinterpret_cast<const bf16x8*>(
                U2t + (size_t)(nt * 16 + m16) * 256 + ks * 32 + quad * 8);
            acc[nt] = __builtin_amdgcn_mfma_f32_16x16x32_bf16(a, b, acc[nt], 0, 0, 0);
        }
    }
    __builtin_amdgcn_sched_barrier(0);

    // phase 4: ZUb stores only (12.8 MB total)
#pragma unroll
    for (int r = 0; r < 4; ++r) {
        int node = nb + w * 16 + quad * 4 + r;
        if (node < n) {
#pragma unroll
            for (int nt = 0; nt < 4; ++nt)
                ZUb[(size_t)node * 64 + nt * 16 + m16] = f2bf(acc[nt][r]);
        }
    }
}

// ---------- per-node aggregation: 1 wave/node, 4 edges in flight; emits bf16 V ----------
// lane = g*16+q: group g handles edge c0+g, lane q holds dims 4q..4q+3 (uint2 bf16x4)
// 2-deep esrc index pipeline + 1-deep ZUb gather pipeline.
__global__ __launch_bounds__(256) void k_agg(const u16* __restrict__ ZUb,
                                             const int* __restrict__ esrc,
                                             const int* __restrict__ off,
                                             const int* __restrict__ cnt,
                                             const float* __restrict__ hwp,
                                             u16* __restrict__ Vb, int n) {
    int node = blockIdx.x * 4 + (threadIdx.x >> 6);
    int lane = threadIdx.x & 63;
    if (node >= n) return;
    const int q = lane & 15;
    const int g = lane >> 4;
    uint2 zdp = *reinterpret_cast<const uint2*>(ZUb + (size_t)node * 64 + q * 4);
    float zd0 = bl(zdp.x), zd1 = bh(zdp.x), zd2 = bl(zdp.y), zd3 = bh(zdp.y);
    int base = off[node];
    int deg = cnt[node];

    int s0 = (g < deg) ? esrc[base + g] : 0;
    int s1 = (4 + g < deg) ? esrc[base + 4 + g] : 0;
    uint2 z0 = *reinterpret_cast<const uint2*>(ZUb + (size_t)s0 * 64 + q * 4);

    float ax = 0.f, ay = 0.f, az = 0.f, aw = 0.f, ssum = 0.f;
    for (int c0 = 0; c0 < deg; c0 += 4) {
        int e2 = c0 + 8 + g;
        int s2 = (e2 < deg) ? esrc[base + e2] : 0;          // index prefetch (k+2)
        uint2 z1 = *reinterpret_cast<const uint2*>(           // gather prefetch (k+1)
            ZUb + (size_t)s1 * 64 + q * 4);
        bool valid = (c0 + g) < deg;
        float v0 = bl(z0.x), v1 = bh(z0.x), v2 = bl(z0.y), v3 = bh(z0.y);
        float p = v0 * zd0 + v1 * zd1 + v2 * zd2 + v3 * zd3;
        p += __shfl_xor(p, 1);
        p += __shfl_xor(p, 2);              // head dot across 4-lane subgroup
        float ew = valid ? __expf(p * 0.25f) : 0.f;   // / sqrt(R)=4
        ax += ew * v0; ay += ew * v1;
        az += ew * v2; aw += ew * v3;
        ssum += ew;
        s1 = s2; z0 = z1;
    }
    ax += __shfl_xor(ax, 16); ax += __shfl_xor(ax, 32);
    ay += __shfl_xor(ay, 16); ay += __shfl_xor(ay, 32);
    az += __shfl_xor(az, 16); az += __shfl_xor(az, 32);
    aw += __shfl_xor(aw, 16); aw += __shfl_xor(aw, 32);
    ssum += __shfl_xor(ssum, 16); ssum += __shfl_xor(ssum, 32);

    if (g == 0) {
        float h0 = hwp[0], h1 = hwp[1], h2 = hwp[2], h3 = hwp[3];
        float mx = fmaxf(fmaxf(h0, h1), fmaxf(h2, h3));
        float e0 = __expf(h0 - mx), e1 = __expf(h1 - mx),
              e2 = __expf(h2 - mx), e3 = __expf(h3 - mx);
        float es = e0 + e1 + e2 + e3;
        int hd = q >> 2;
        float wk = (hd == 0 ? e0 : hd == 1 ? e1 : hd == 2 ? e2 : e3) / es;
        float inv = wk / ssum;
        uint2 pk;
        pk.x = (u32)f2bf(ax * inv) | ((u32)f2bf(ay * inv) << 16);
        pk.y = (u32)f2bf(az * inv) | ((u32)f2bf(aw * inv) << 16);
        *reinterpret_cast<uint2*>(&Vb[(size_t)node * 64 + q * 4]) = pk;
    }
}

// ---------- final fused GEMM: out = relu([bf16(Z)|Vb] @ Bt^T - 0.05), K=320 ----------
// R9: stages directly from Z (fp32), casts during staging (no Zb intermediate).
// Chunk (row, col=ks*4+q) <- two float4 at z-bytes row*1024+ks*128+q*16 (+64):
// each staging instruction covers full 64B segments. LDS layout/swizzle unchanged;
// Bt rows k<256 are kperm'd (prep3) to match. Vb tile via async global_load_lds.
__global__ __launch_bounds__(256, 4) void k_out(const float* __restrict__ Z,
                                                const u16* __restrict__ Vb,
                                                const u16* __restrict__ Bt,
                                                float* __restrict__ out, int n) {
    __shared__ __align__(16) u16 sA[64 * 256];   // 32 KB, rows 512B (32 chunks)
    __shared__ __align__(16) u16 sV[64 * 64];    //  8 KB, rows 128B (8 chunks)
    const int t = threadIdx.x;
    const int w = t >> 6;
    const int lane = t & 63;
    const int m16 = lane & 15;          // A row / D col within tile
    const int quad = lane >> 4;         // k-subblock / D row group
    const int nb = blockIdx.x * 64;

    // stage Vb tile first (async, overlaps the Z staging below)
#pragma unroll
    for (int i = 0; i < 2; ++i) {
        int c = i * 256 + w * 64 + lane;
        int row = c >> 3, col = c & 7;
        int scol = col ^ (row & 7);
        int gr = nb + row; if (gr >= n) gr = n - 1;
        gload_lds16(Vb + (size_t)gr * 64 + scol * 8,
                    sV + (size_t)(i * 256 + w * 64) * 8);
    }

    // stage Z tile: 2048 chunks, 8 per thread; load fp32 pair, cast, swizzled ds_write
#pragma unroll
    for (int i = 0; i < 8; ++i) {
        int c = i * 256 + t;
        int row = c >> 5, col = c & 31;
        int ks = col >> 2, q = col & 3;
        int gr = nb + row; if (gr >= n) gr = n - 1;
        const char* zrow = (const char*)(Z + (size_t)gr * 256);
        float4 a0 = *reinterpret_cast<const float4*>(zrow + ks * 128 + q * 16);
        float4 a1 = *reinterpret_cast<const float4*>(zrow + ks * 128 + 64 + q * 16);
        uint4 pk;
        pk.x = (u32)f2bf(a0.x) | ((u32)f2bf(a0.y) << 16);
        pk.y = (u32)f2bf(a0.z) | ((u32)f2bf(a0.w) << 16);
        pk.z = (u32)f2bf(a1.x) | ((u32)f2bf(a1.y) << 16);
        pk.w = (u32)f2bf(a1.z) | ((u32)f2bf(a1.w) << 16);
        *reinterpret_cast<uint4*>((char*)sA + row * 512 + ((col ^ (row & 7)) << 4)) = pk;
    }
    __syncthreads();   // drains vmcnt (incl. the async Vb loads) before use

    f32x4 acc[4][4];
#pragma unroll
    for (int mt = 0; mt < 4; ++mt)
#pragma unroll
        for (int nt = 0; nt < 4; ++nt)
            acc[mt][nt] = (f32x4){0.f, 0.f, 0.f, 0.f};

    const u16* bbase4[4];
#pragma unroll
    for (int nt = 0; nt < 4; ++nt)
        bbase4[nt] = Bt + (size_t)(w * 64 + nt * 16 + m16) * 320 + quad * 8;

    const u32 asw = (u32)(m16 & 7) << 4;

    for (int ks = 0; ks < 8; ++ks) {
        bf16x8 a[4], b[4];
#pragma unroll
        for (int mt = 0; mt < 4; ++mt)
            a[mt] = *reinterpret_cast<const bf16x8*>(
                (char*)sA + (u32)(mt * 16 + m16) * 512 +
                (((u32)(ks * 64 + quad * 16)) ^ asw));
#pragma unroll
        for (int nt = 0; nt < 4; ++nt)
            b[nt] = *reinterpret_cast<const bf16x8*>(bbase4[nt] + ks * 32);
#pragma unroll
        for (int mt = 0; mt < 4; ++mt)
#pragma unroll
            for (int nt = 0; nt < 4; ++nt)
                acc[mt][nt] = __builtin_amdgcn_mfma_f32_16x16x32_bf16(
                    a[mt], b[nt], acc[mt][nt], 0, 0, 0);
    }
#pragma unroll
    for (int ks = 8; ks < 10; ++ks) {
        bf16x8 a[4], b[4];
#pragma unroll
        for (int mt = 0; mt < 4; ++mt)
            a[mt] = *reinterpret_cast<const bf16x8*>(
                (char*)sV + (u32)(mt * 16 + m16) * 128 +
                (((u32)((ks - 8) * 64 + quad * 16)) ^ asw));
#pragma unroll
        for (int nt = 0; nt < 4; ++nt)
            b[nt] = *reinterpret_cast<const bf16x8*>(bbase4[nt] + ks * 32);
#pragma unroll
        for (int mt = 0; mt < 4; ++mt)
#pragma unroll
            for (int nt = 0; nt < 4; ++nt)
                acc[mt][nt] = __builtin_amdgcn_mfma_f32_16x16x32_bf16(
                    a[mt], b[nt], acc[mt][nt], 0, 0, 0);
    }

#pragma unroll
    for (int mt = 0; mt < 4; ++mt) {
#pragma unroll
        for (int r = 0; r < 4; ++r) {
            int row = nb + mt * 16 + quad * 4 + r;
            if (row < n) {
#pragma unroll
                for (int nt = 0; nt < 4; ++nt) {
                    int col = w * 64 + nt * 16 + m16;
                    out[(size_t)row * 256 + col] =
                        fmaxf(acc[mt][nt][r] - 0.05f, 0.f);
                }
            }
        }
    }
}

extern "C" void kernel_launch(void* const* d_in, const int* in_sizes, int n_in,
                              void* d_out, int out_size, void* d_ws, size_t ws_size,
                              hipStream_t stream) {
    const float* Z  = (const float*)d_in[0];
    const float* U  = (const float*)d_in[1];
    const float* Dm = (const float*)d_in[2];
    const float* hw = (const float*)d_in[3];
    const int*   ei = (const int*)d_in[4];
    const int n = in_sizes[0] / 256;       // 100000
    const int E = in_sizes[4] / 2;         // 1700000
    float* out = (float*)d_out;
    const int nbuck = (n + 255) >> 8;      // 391 (<= 512)

    // ws layout, lifetime-aliased:
    //   ZUb  bf16 n*64   (12.8 MB)  k_zumm -> k_agg
    //   scratch region (was Zb, now CSR-only): part int E | cnt2 | pre2
    //   Vb   bf16 n*64   (12.8 MB)  k_agg -> k_out
    //   G, A fp32 64K ea; Bt bf16 256*320; U2t bf16 64*256
    //   esrc int E (6.8 MB)  k_bucket -> k_agg
    //   off, cnt int n; tot, bbase int nbuck
    char* wp = (char*)d_ws;
    u16* ZUb    = (u16*)wp;
    u16* Zb     = (u16*)(wp + (size_t)n * 128);   // scratch base (CSR build only)
    int* part   = (int*)Zb;
    int* cnt2   = part + E;
    int* pre2   = cnt2 + PB * nbuck;
    u16* Vb     = Zb + (size_t)n * 256;
    float* G    = (float*)(Vb + (size_t)n * 64);
    float* A    = G + 65536;
    u16* Bt     = (u16*)(A + 65536);
    u16* U2t    = Bt + 256 * 320;
    int* esrc   = (int*)(U2t + 64 * 256);
    int* off    = esrc + E;
    int* cnt    = off + n;
    int* tot    = cnt + n;
    int* bbase  = tot + nbuck;

    // prep (tiny)
    k_prep1<<<256, 256, 0, stream>>>(Dm, G);
    k_prep2<<<256, 256, 0, stream>>>(Dm, G, A);
    k_prep3<<<256, 256, 0, stream>>>(A, Bt);
    k_prep4<<<64, 256, 0, stream>>>(U, A, Bt);
    k_prep5<<<64, 256, 0, stream>>>(U, U2t);

    // CSR build
    k_cnt1<<<PB, 256, 0, stream>>>(ei, cnt2, E, nbuck);
    k_cscan1<<<nbuck, 256, 0, stream>>>(cnt2, pre2, tot, nbuck);
    k_cscan2<<<1, 512, 0, stream>>>(tot, bbase, nbuck);
    k_place<<<PB, 256, 0, stream>>>(ei, pre2, bbase, part, E, nbuck);
    k_bucket<<<nbuck, 256, 0, stream>>>(part, tot, bbase, off, cnt, esrc, n);

    // main pipeline (no Zb intermediate)
    k_zumm<<<(n + 63) / 64, 256, 0, stream>>>(Z, U2t, ZUb, n);
    k_agg<<<(n + 3) / 4, 256, 0, stream>>>(ZUb, esrc, off, cnt, hw, Vb, n);
    k_out<<<(n + 63) / 64, 256, 0, stream>>>(Z, Vb, Bt, out, n);
}